// Round 4
// baseline (516.687 us; speedup 1.0000x reference)
//
#include <hip/hip_runtime.h>
#include <math.h>

#define KCLS 21
#define BATCH 16
#define HF 41
#define WF 41
#define HH 321
#define WW 321
#define CFEAT 2048
#define HWF (HF*WF)            // 1681
#define HWI (HH*WW)            // 103041
#define NPIX (BATCH*HWI)       // 1648656
#define NBLK_C ((NPIX + 255)/256)  // 6441
#define EPSC 1e-6f

__device__ float g_wn[KCLS];
__device__ float g_corr[(size_t)BATCH*KCLS*HWF];
__device__ float g_part[6][NBLK_C];

// ---------------- kernel A: classifier weight row norms ----------------
__global__ __launch_bounds__(256) void k_wn(const float* __restrict__ cw) {
    int wave = threadIdx.x >> 6, lane = threadIdx.x & 63;
    for (int k = wave; k < KCLS; k += 4) {
        float s = 0.f;
        for (int c = lane; c < CFEAT; c += 64) {
            float v = cw[k*CFEAT + c];
            s = fmaf(v, v, s);
        }
        #pragma unroll
        for (int off = 32; off; off >>= 1) s += __shfl_down(s, off, 64);
        if (lane == 0) g_wn[k] = sqrtf(s);
    }
}

// ---------------- kernel B: corr map at 41x41 ----------------
// grid (27, 16), block 512 (8 waves). 64 pixels/block (one per lane of each
// wave), C split into 8 wave-chunks of 256; chunk id forced to SGPR so the
// 21 classifier-weight float4 loads scalarize (s_load_dwordx4).
__global__ __launch_bounds__(512) void k_corr(const float* __restrict__ fm,
                                              const float* __restrict__ cw) {
    int b = blockIdx.y;
    int lane = threadIdx.x & 63;
    int chunk = __builtin_amdgcn_readfirstlane(threadIdx.x >> 6);  // 0..7, SGPR
    int hw = blockIdx.x * 64 + lane;
    bool valid = hw < HWF;
    const float* fbase = fm + (size_t)b * CFEAT * HWF + (valid ? hw : 0);
    int cbase = chunk * (CFEAT / 8);

    float acc[KCLS];
    #pragma unroll
    for (int k = 0; k < KCLS; ++k) acc[k] = 0.f;
    float nrm = 0.f;

    for (int j = 0; j < CFEAT/8; j += 4) {
        int c = cbase + j;
        float f0 = fbase[(size_t)(c+0)*HWF];
        float f1 = fbase[(size_t)(c+1)*HWF];
        float f2 = fbase[(size_t)(c+2)*HWF];
        float f3 = fbase[(size_t)(c+3)*HWF];
        nrm = fmaf(f0,f0, fmaf(f1,f1, fmaf(f2,f2, fmaf(f3,f3, nrm))));
        #pragma unroll
        for (int k = 0; k < KCLS; ++k) {
            // all-scalar address -> s_load_dwordx4
            const float4 wv = *reinterpret_cast<const float4*>(cw + (size_t)k*CFEAT + c);
            acc[k] = fmaf(f0,wv.x, fmaf(f1,wv.y, fmaf(f2,wv.z, fmaf(f3,wv.w, acc[k]))));
        }
    }

    __shared__ float red[KCLS+1][8][64];
    #pragma unroll
    for (int k = 0; k < KCLS; ++k) red[k][chunk][lane] = acc[k];
    red[KCLS][chunk][lane] = nrm;
    __syncthreads();

    if (threadIdx.x < 64) {
        int p = lane;
        int hw2 = blockIdx.x * 64 + p;
        if (hw2 < HWF) {
            float n8 = 0.f;
            #pragma unroll
            for (int j = 0; j < 8; ++j) n8 += red[KCLS][j][p];
            float fn = sqrtf(n8);
            float* out = g_corr + (size_t)b * KCLS * HWF + hw2;
            #pragma unroll
            for (int k = 0; k < KCLS; ++k) {
                float d = 0.f;
                #pragma unroll
                for (int j = 0; j < 8; ++j) d += red[k][j][p];
                float den = fmaxf(fn * g_wn[k], EPSC);
                out[(size_t)k * HWF] = 1.f + d / den;
            }
        }
    }
}

// ---------------- kernel C: main pass over 321x321 pixels ----------------
__global__ __launch_bounds__(256) void k_main(const float* __restrict__ yp,
                                              const int* __restrict__ ycrf,
                                              const int* __restrict__ yret) {
    int tid = threadIdx.x;
    int p = blockIdx.x * 256 + tid;
    float a0=0.f, a1=0.f, a2=0.f, a3=0.f, a4=0.f, a5=0.f;
    if (p < NPIX) {
        int b = p / HWI;
        int r = p - b * HWI;
        int h = r / WW;
        int w = r - h * WW;
        int c = ycrf[p];
        bool match = (c == yret[p]);

        const float* ybase = yp + (size_t)b * KCLS * HWI + r;
        float v[KCLS];
        float mx = -1e30f, sum_y = 0.f;
        #pragma unroll
        for (int k = 0; k < KCLS; ++k) {
            v[k] = ybase[(size_t)k * HWI];
            sum_y += v[k];
            mx = fmaxf(mx, v[k]);
        }
        float se = 0.f, yc = 0.f;
        #pragma unroll
        for (int k = 0; k < KCLS; ++k) {
            se += __expf(v[k] - mx);
            yc = (k == c) ? v[k] : yc;
        }
        float lse = __logf(se);
        float logp_c = yc - mx - lse;
        float sum_logp = sum_y - (float)KCLS * (mx + lse);

        // half-pixel bilinear coords, clamp-to-edge (== jax renormalized tri)
        const float S = (float)HF / (float)HH;
        float xf = ((float)w + 0.5f) * S - 0.5f;
        float yf = ((float)h + 0.5f) * S - 0.5f;
        float xg = floorf(xf), yg = floorf(yf);
        float fx = xf - xg, fy = yf - yg;
        int ix0 = (int)xg; if (ix0 < 0) ix0 = 0;
        int iy0 = (int)yg; if (iy0 < 0) iy0 = 0;
        int ix1 = (int)xg + 1; if (ix1 > WF-1) ix1 = WF-1; if (ix1 < 0) ix1 = 0;
        int iy1 = (int)yg + 1; if (iy1 > HF-1) iy1 = HF-1; if (iy1 < 0) iy1 = 0;
        float w00 = (1.f-fx)*(1.f-fy), w01 = fx*(1.f-fy);
        float w10 = (1.f-fx)*fy,       w11 = fx*fy;
        int o00 = iy0*WF+ix0, o01 = iy0*WF+ix1, o10 = iy1*WF+ix0, o11 = iy1*WF+ix1;

        const float* cb = g_corr + (size_t)b * KCLS * HWF;
        float cmax = -1e30f, cstar = 0.f;
        #pragma unroll
        for (int k = 0; k < KCLS; ++k) {
            const float* ck = cb + (size_t)k * HWF;
            float cv = w00*ck[o00] + w01*ck[o01] + w10*ck[o10] + w11*ck[o11];
            cmax = fmaxf(cmax, cv);
            cstar = (k == c) ? cv : cstar;
        }
        float ratio = cstar / cmax;
        float conf = ratio * ratio;
        float mf = match ? 1.f : 0.f;

        a0 = match ? logp_c : 0.f;   // sum match*logp_c
        a1 = mf;                     // cnt
        a2 = conf * sum_logp;        // sum conf*sum_logp
        a3 = mf * conf * logp_c;     // sum m*conf*logp_c
        a4 = conf;                   // sum conf
        a5 = mf * conf;              // sum m*conf
    }

    #pragma unroll
    for (int off = 32; off; off >>= 1) {
        a0 += __shfl_down(a0, off, 64);
        a1 += __shfl_down(a1, off, 64);
        a2 += __shfl_down(a2, off, 64);
        a3 += __shfl_down(a3, off, 64);
        a4 += __shfl_down(a4, off, 64);
        a5 += __shfl_down(a5, off, 64);
    }
    __shared__ float s[4][6];
    int wave = tid >> 6, lane = tid & 63;
    if (lane == 0) {
        s[wave][0]=a0; s[wave][1]=a1; s[wave][2]=a2;
        s[wave][3]=a3; s[wave][4]=a4; s[wave][5]=a5;
    }
    __syncthreads();
    if (tid == 0) {
        #pragma unroll
        for (int j = 0; j < 6; ++j)
            g_part[j][blockIdx.x] = s[0][j] + s[1][j] + s[2][j] + s[3][j];
    }
}

// ---------------- kernel D: final reduce + loss ----------------
__global__ __launch_bounds__(256) void k_final(float* __restrict__ out) {
    int tid = threadIdx.x;
    float s[6] = {0,0,0,0,0,0};
    for (int i = tid; i < NBLK_C; i += 256) {
        #pragma unroll
        for (int j = 0; j < 6; ++j) s[j] += g_part[j][i];
    }
    #pragma unroll
    for (int j = 0; j < 6; ++j) {
        #pragma unroll
        for (int off = 32; off; off >>= 1) s[j] += __shfl_down(s[j], off, 64);
    }
    __shared__ float red[4][6];
    int wave = tid >> 6, lane = tid & 63;
    if (lane == 0) {
        #pragma unroll
        for (int j = 0; j < 6; ++j) red[wave][j] = s[j];
    }
    __syncthreads();
    if (tid == 0) {
        float A    = red[0][0]+red[1][0]+red[2][0]+red[3][0];
        float CNT  = red[0][1]+red[1][1]+red[2][1]+red[3][1];
        float Scs  = red[0][2]+red[1][2]+red[2][2]+red[3][2];
        float Smcl = red[0][3]+red[1][3]+red[2][3]+red[3][3];
        float Sc   = red[0][4]+red[1][4]+red[2][4]+red[3][4];
        float Smc  = red[0][5]+red[1][5]+red[2][5]+red[3][5];
        float loss_ce  = -A / CNT;
        float numer = Scs - Smcl;
        float denom = (float)KCLS * Sc - Smc;
        float loss_wce = -numer / denom;
        out[0] = loss_ce + loss_wce;
    }
}

extern "C" void kernel_launch(void* const* d_in, const int* in_sizes, int n_in,
                              void* d_out, int out_size, void* d_ws, size_t ws_size,
                              hipStream_t stream) {
    const float* y_pred = (const float*)d_in[0];
    const int*   ycrf   = (const int*)d_in[1];
    const int*   yret   = (const int*)d_in[2];
    const float* fm     = (const float*)d_in[3];
    const float* cw     = (const float*)d_in[4];
    float* out = (float*)d_out;

    k_wn  <<<1, 256, 0, stream>>>(cw);
    k_corr<<<dim3((HWF+63)/64, BATCH), 512, 0, stream>>>(fm, cw);
    k_main<<<NBLK_C, 256, 0, stream>>>(y_pred, ycrf, yret);
    k_final<<<1, 256, 0, stream>>>(out);
}